// Round 17
// baseline (430.080 us; speedup 1.0000x reference)
//
#include <hip/hip_runtime.h>
#include <math.h>

#define DD 4096
#define EE 64
#define NTOK 8192
#define BM 128           // tokens per block
#define KC 32            // K-chunk per pipeline step
#define NMB (NTOK / BM)  // 64 m-blocks
#define KS 8             // K-split
#define WSTR 40          // W LDS row stride in bf16 (80 B, 16B-aligned)
#define TAU 4e-3f        // near-tie flag threshold (split err ~1e-5 RMS)

typedef __attribute__((ext_vector_type(8))) short short8;
typedef __attribute__((ext_vector_type(4))) float f32x4;

__device__ __forceinline__ unsigned short f2bf(float f) {   // RNE bf16
    unsigned int u = __float_as_uint(f);
    return (unsigned short)((u + 0x7FFFu + ((u >> 16) & 1u)) >> 16);
}
__device__ __forceinline__ float bf2f(unsigned short h) {
    return __uint_as_float((unsigned int)h << 16);
}

// ---------------------------------------------------------------------------
// gemm + fused split-K reduce/topk.
// Core = r13/r14 validated structure: 256 thr (4 waves) = 128 tok x 64 exp
// per K-slice; x via global_load_lds (src-swizzled k^4(r&7)); W f32->reg->
// cvt hi/lo->ds_write (no prep kernel); double LDS buffer, 2 barriers/step.
// Epilogue: partials -> threadfence -> atomicAdd(ready[mblk]); the block
// seeing old%KS==KS-1 reduces all KS slices in FIXED order (deterministic),
// does ballot top-3 (r16-validated), writes out + flag[token] (0/1 always
// overwritten -> no reset needed; mod-KS trigger correct under 0xAA poison).
// ---------------------------------------------------------------------------
__global__ __launch_bounds__(256, 2) void moirai_gemm(
        const float* __restrict__ x,
        const float* __restrict__ W,
        const float* __restrict__ bias,
        float* __restrict__ part,
        int* __restrict__ ready,
        unsigned char* __restrict__ flag,
        float* __restrict__ out) {
    __shared__ __align__(16) float          xs[2][BM * KC];     // 32 KB
    __shared__ __align__(16) unsigned short whs[2][EE * WSTR];  // 10 KB
    __shared__ __align__(16) unsigned short wls[2][EE * WSTR];  // 10 KB
    __shared__ int is_last;

    const int t    = threadIdx.x;
    const int lane = t & 63;
    const int wv   = t >> 6;             // wave 0..3
    const int mblk = blockIdx.x & (NMB - 1);
    const int ks   = blockIdx.x >> 6;    // grid = NMB * KS
    const int m0   = mblk * BM;
    const int k0   = ks * (DD / KS);

    const int fr = lane & 15;            // fragment row (token / expert)
    const int fg = lane >> 4;            // k-group (8 elems)

    const int we  = t >> 2;              // W staging: row 0..63
    const int wsg = t & 3;               // 8-elem segment 0..3

    f32x4 accH[2][4], accL[2][4];
#pragma unroll
    for (int mf = 0; mf < 2; mf++)
#pragma unroll
        for (int nt = 0; nt < 4; nt++) {
            accH[mf][nt] = f32x4{0.f, 0.f, 0.f, 0.f};
            accL[mf][nt] = f32x4{0.f, 0.f, 0.f, 0.f};
        }

    // x staging: wave wv issues 4 global_load_lds (1 KB each, LDS-linear).
    auto stage_x = [&](int p, int c) {
        const int kb = k0 + c * KC;
#pragma unroll
        for (int j = 0; j < 4; j++) {
            const int r = wv * 32 + j * 8 + (lane >> 3);
            const int k = ((lane & 7) * 4) ^ (4 * (r & 7));
            const float* gp = x + (size_t)(m0 + r) * DD + kb + k;
            float* lp = &xs[p][(wv * 4 + j) * 256];   // wave-uniform base
            __builtin_amdgcn_global_load_lds(
                (const __attribute__((address_space(1))) void*)gp,
                (__attribute__((address_space(3))) void*)lp, 16, 0, 0);
        }
    };

    float4 wr0, wr1;
    auto ldW = [&](int c) {
        const int kb = k0 + c * KC;
        wr0 = *(const float4*)(W + (size_t)we * DD + kb + wsg * 8);
        wr1 = *(const float4*)(W + (size_t)we * DD + kb + wsg * 8 + 4);
    };
    auto stW = [&](int p) {
        const float v[8] = {wr0.x, wr0.y, wr0.z, wr0.w,
                            wr1.x, wr1.y, wr1.z, wr1.w};
        short8 h, l;
#pragma unroll
        for (int i = 0; i < 8; i++) {
            unsigned short hh = f2bf(v[i]);
            h[i] = (short)hh;
            l[i] = (short)f2bf(v[i] - bf2f(hh));
        }
        *(short8*)&whs[p][we * WSTR + wsg * 8] = h;
        *(short8*)&wls[p][we * WSTR + wsg * 8] = l;
    };

    auto compute = [&](int p) {
        short8 ah[2], al[2], bh[4], bl[4];
#pragma unroll
        for (int mf = 0; mf < 2; mf++) {
            const int r = (wv * 2 + mf) * 16 + fr;
            const int q = 4 * (fr & 7);          // r&7 == fr&7
            const float4 a0 = *(const float4*)&xs[p][r * 32 + ((fg * 8) ^ q)];
            const float4 a1 = *(const float4*)&xs[p][r * 32 + ((fg * 8 + 4) ^ q)];
            const float v[8] = {a0.x, a0.y, a0.z, a0.w, a1.x, a1.y, a1.z, a1.w};
#pragma unroll
            for (int i = 0; i < 8; i++) {
                unsigned short hh = f2bf(v[i]);
                ah[mf][i] = (short)hh;
                al[mf][i] = (short)f2bf(v[i] - bf2f(hh));
            }
        }
#pragma unroll
        for (int nt = 0; nt < 4; nt++) {
            const int e = nt * 16 + fr;
            bh[nt] = *(const short8*)&whs[p][e * WSTR + fg * 8];
            bl[nt] = *(const short8*)&wls[p][e * WSTR + fg * 8];
        }
#pragma unroll
        for (int mf = 0; mf < 2; mf++)
#pragma unroll
            for (int nt = 0; nt < 4; nt++) {
                accH[mf][nt] = __builtin_amdgcn_mfma_f32_16x16x32_bf16(
                    ah[mf], bh[nt], accH[mf][nt], 0, 0, 0);
                accL[mf][nt] = __builtin_amdgcn_mfma_f32_16x16x32_bf16(
                    ah[mf], bl[nt], accL[mf][nt], 0, 0, 0);
                accL[mf][nt] = __builtin_amdgcn_mfma_f32_16x16x32_bf16(
                    al[mf], bh[nt], accL[mf][nt], 0, 0, 0);
            }
    };

    const int nch = (DD / KS) / KC;      // 16
    ldW(0);
    stage_x(0, 0);
    stW(0);
    __syncthreads();                     // buf 0 staged & visible

    for (int c = 0; c < nch; c++) {
        const int p = c & 1;
        if (c + 1 < nch) {
            stage_x(p ^ 1, c + 1);       // async DMA into other buffer
            ldW(c + 1);                  // W regs in flight under compute
        }
        compute(p);
        if (c + 1 < nch) stW(p ^ 1);     // vmcnt wait auto-inserted here
        __syncthreads();                 // drain + visibility, once per step
    }

    // C/D (verified m89/m91): col = lane&15 -> expert, row = fg*4+j -> token
#pragma unroll
    for (int mf = 0; mf < 2; mf++)
#pragma unroll
        for (int nt = 0; nt < 4; nt++)
#pragma unroll
            for (int j = 0; j < 4; j++) {
                const int token = m0 + (wv * 2 + mf) * 16 + fg * 4 + j;
                const float v = accH[mf][nt][j] + accL[mf][nt][j];
                part[((size_t)ks * NTOK + token) * EE + nt * 16 + fr] = v;
            }

    // ---- split-K semaphore: last block of this m-group reduces ----
    __threadfence();                     // release: partials visible
    if (t == 0) {
        int old = atomicAdd(&ready[mblk], 1);
        is_last = ((old % KS) == (KS - 1)) ? 1 : 0;
    }
    __syncthreads();
    if (!is_last) return;
    __threadfence();                     // acquire: see all KS slices

    const float blv = bias[lane];
    for (int r = 0; r < 32; r++) {       // wave wv -> tokens wv*32+r
        const int tok = m0 + wv * 32 + r;
        float v = blv;
#pragma unroll
        for (int k2 = 0; k2 < KS; k2++)  // fixed order: deterministic
            v += part[((size_t)k2 * NTOK + tok) * EE + lane];

        float m1 = v;
#pragma unroll
        for (int off = 1; off < 64; off <<= 1) m1 = fmaxf(m1, __shfl_xor(m1, off));
        const unsigned long long b1 = __ballot(v == m1);
        const int i1 = (int)__ffsll(b1) - 1;          // lowest index (jax)

        const float vm2 = (lane == i1) ? -3.4e38f : v;
        float m2 = vm2;
#pragma unroll
        for (int off = 1; off < 64; off <<= 1) m2 = fmaxf(m2, __shfl_xor(m2, off));
        const unsigned long long b2 = __ballot(vm2 == m2 && lane != i1);
        const int i2 = (int)__ffsll(b2) - 1;

        const float vm3 = (lane == i1 || lane == i2) ? -3.4e38f : v;
        float m3 = vm3;
#pragma unroll
        for (int off = 1; off < 64; off <<= 1) m3 = fmaxf(m3, __shfl_xor(m3, off));

        if (lane == 0) {
            flag[tok] = ((m1 - m2 < TAU) || (m2 - m3 < TAU)) ? 1 : 0;
            double ex = exp((double)m2 - (double)m1);  // m1 >= m2 -> stable
            double s  = 1.0 + ex;
            out[tok * 2 + 0] = (float)(1.0 / s);
            out[tok * 2 + 1] = (float)(ex / s);
            out[NTOK * 2 + tok * 2 + 0] = (float)i1;
            out[NTOK * 2 + tok * 2 + 1] = (float)i2;
        }
    }
}

// ---------------------------------------------------------------------------
// fix: exact f64 recompute of flagged rows. Grid 256, block 1024; block b
// owns tokens b + i*256 (i=0..31); flags preloaded to LDS (block-uniform
// branch). x row staged in LDS; 16 lanes/expert -> coalesced 64B W reads;
// shfl-tree reduce -> wave 0 f64 top-2 (validated comparator).
// ---------------------------------------------------------------------------
__global__ __launch_bounds__(1024) void moirai_fix(
        const float* __restrict__ x, const float* __restrict__ W,
        const float* __restrict__ bias,
        const unsigned char* __restrict__ flag,
        float* __restrict__ out) {
    __shared__ float  xsr[DD];      // 16 KB
    __shared__ double red[EE];
    __shared__ unsigned char flg[32];

    const int t = threadIdx.x;
    const int e = t >> 4;           // expert 0..63
    const int j = t & 15;           // k-strip within expert

    if (t < 32) flg[t] = flag[blockIdx.x + t * 256];
    __syncthreads();

    for (int i = 0; i < 32; i++) {
        if (!flg[i]) continue;                 // block-uniform
        const int token = blockIdx.x + i * 256;

        *(float4*)&xsr[t * 4] = *(const float4*)(x + (size_t)token * DD + t * 4);
        __syncthreads();

        const float* wr = W + (size_t)e * DD;
        double a0 = 0.0, a1 = 0.0, a2 = 0.0, a3 = 0.0;
#pragma unroll 8
        for (int ii = 0; ii < DD / 64; ii++) {
            const int k = ii * 64 + j * 4;
            const float4 xv = *(const float4*)&xsr[k];
            const float4 wv = *(const float4*)(wr + k);
            a0 += (double)xv.x * (double)wv.x;
            a1 += (double)xv.y * (double)wv.y;
            a2 += (double)xv.z * (double)wv.z;
            a3 += (double)xv.w * (double)wv.w;
        }
        double s = (a0 + a1) + (a2 + a3);
#pragma unroll
        for (int off = 1; off < 16; off <<= 1)
            s += __shfl_xor(s, off);           // within 16-lane group
        if (j == 0) red[e] = s;
        __syncthreads();

        if (t < 64) {                          // wave 0: f64 top-2
            double vd = red[t] + (double)bias[t];
            double e1 = vd, e2 = -1.0e300;
            int    f1 = t,  f2 = 127;
#pragma unroll
            for (int off = 1; off < 64; off <<= 1) {
                double u1 = __shfl_xor(e1, off);
                double u2 = __shfl_xor(e2, off);
                int    j1 = __shfl_xor(f1, off);
                int    j2 = __shfl_xor(f2, off);
                bool u1_beats_e1 = (u1 > e1) || (u1 == e1 && j1 < f1);
                if (u1_beats_e1) {
                    bool e1_beats_u2 = (e1 > u2) || (e1 == u2 && f1 < j2);
                    if (e1_beats_u2) { e2 = e1; f2 = f1; }
                    else             { e2 = u2; f2 = j2; }
                    e1 = u1; f1 = j1;
                } else {
                    bool u1_beats_e2 = (u1 > e2) || (u1 == e2 && j1 < f2);
                    if (u1_beats_e2) { e2 = u1; f2 = j1; }
                }
            }
            if (t == 0) {
                double ex = exp(e2 - e1);
                double sm = 1.0 + ex;
                out[token * 2 + 0] = (float)(1.0 / sm);
                out[token * 2 + 1] = (float)(ex / sm);
                out[NTOK * 2 + token * 2 + 0] = (float)f1;
                out[NTOK * 2 + token * 2 + 1] = (float)f2;
            }
        }
        __syncthreads();   // LDS reuse guard
    }
}

// ---------------------------------------------------------------------------
extern "C" void kernel_launch(void* const* d_in, const int* in_sizes, int n_in,
                              void* d_out, int out_size, void* d_ws, size_t ws_size,
                              hipStream_t stream) {
    const float* x = (const float*)d_in[0];
    const float* W = (const float*)d_in[1];
    const float* b = (const float*)d_in[2];
    float* out = (float*)d_out;

    // ws layout: [ready: 64 int][flag: 8192 B] padded to 64 KB, then partials.
    // ready is never reset: trigger is (old % KS == KS-1), correct for any
    // initial value (incl. 0xAA poison). flag is fully overwritten each call.
    const size_t HDR = 65536;
    int*           ready = (int*)d_ws;
    unsigned char* flag  = (unsigned char*)d_ws + 256;
    float*         part  = (float*)((char*)d_ws + HDR);

    moirai_gemm<<<NMB * KS, 256, 0, stream>>>(x, W, b, part, ready, flag, out);
    moirai_fix<<<256, 1024, 0, stream>>>(x, W, b, flag, out);
}

// Round 18
// 180.172 us; speedup vs baseline: 2.3871x; 2.3871x over previous
//
#include <hip/hip_runtime.h>
#include <math.h>

#define DD 4096
#define EE 64
#define NTOK 8192
#define BM 128           // tokens per block
#define KC 32            // K-chunk per pipeline step
#define NMB (NTOK / BM)  // 64 m-blocks
#define KS 8             // K-split
#define WSTR 40          // W LDS row stride in bf16 (80 B, 16B-aligned)
#define TAU 4e-3f        // near-tie flag threshold (split err ~1e-5 RMS)

typedef __attribute__((ext_vector_type(8))) short short8;
typedef __attribute__((ext_vector_type(4))) float f32x4;

__device__ __forceinline__ unsigned short f2bf(float f) {   // RNE bf16
    unsigned int u = __float_as_uint(f);
    return (unsigned short)((u + 0x7FFFu + ((u >> 16) & 1u)) >> 16);
}
__device__ __forceinline__ float bf2f(unsigned short h) {
    return __uint_as_float((unsigned int)h << 16);
}

// ---------------------------------------------------------------------------
// gemm + fused split-K reduce/topk.
// Core = r13/r14 validated structure: 256 thr (4 waves) = 128 tok x 64 exp
// per K-slice; x via global_load_lds (src-swizzled k^4(r&7)); W f32->reg->
// cvt hi/lo->ds_write (no prep kernel); double LDS buffer, 2 barriers/step.
// Epilogue: partials -> threadfence -> atomicAdd(ready[mblk]); the block
// seeing UNSIGNED old%KS==KS-1 reduces all KS slices in FIXED order
// (deterministic), ballot top-3, writes out + flag[token].
// NOTE (r17 bug): trigger MUST be unsigned — 0xAA poison is negative as int
// and signed % never yields KS-1, silently disabling the reducer on replay.
// ---------------------------------------------------------------------------
__global__ __launch_bounds__(256, 2) void moirai_gemm(
        const float* __restrict__ x,
        const float* __restrict__ W,
        const float* __restrict__ bias,
        float* __restrict__ part,
        int* __restrict__ ready,
        unsigned char* __restrict__ flag,
        float* __restrict__ out) {
    __shared__ __align__(16) float          xs[2][BM * KC];     // 32 KB
    __shared__ __align__(16) unsigned short whs[2][EE * WSTR];  // 10 KB
    __shared__ __align__(16) unsigned short wls[2][EE * WSTR];  // 10 KB
    __shared__ int is_last;

    const int t    = threadIdx.x;
    const int lane = t & 63;
    const int wv   = t >> 6;             // wave 0..3
    const int mblk = blockIdx.x & (NMB - 1);
    const int ks   = blockIdx.x >> 6;    // grid = NMB * KS
    const int m0   = mblk * BM;
    const int k0   = ks * (DD / KS);

    const int fr = lane & 15;            // fragment row (token / expert)
    const int fg = lane >> 4;            // k-group (8 elems)

    const int we  = t >> 2;              // W staging: row 0..63
    const int wsg = t & 3;               // 8-elem segment 0..3

    f32x4 accH[2][4], accL[2][4];
#pragma unroll
    for (int mf = 0; mf < 2; mf++)
#pragma unroll
        for (int nt = 0; nt < 4; nt++) {
            accH[mf][nt] = f32x4{0.f, 0.f, 0.f, 0.f};
            accL[mf][nt] = f32x4{0.f, 0.f, 0.f, 0.f};
        }

    // x staging: wave wv issues 4 global_load_lds (1 KB each, LDS-linear).
    auto stage_x = [&](int p, int c) {
        const int kb = k0 + c * KC;
#pragma unroll
        for (int j = 0; j < 4; j++) {
            const int r = wv * 32 + j * 8 + (lane >> 3);
            const int k = ((lane & 7) * 4) ^ (4 * (r & 7));
            const float* gp = x + (size_t)(m0 + r) * DD + kb + k;
            float* lp = &xs[p][(wv * 4 + j) * 256];   // wave-uniform base
            __builtin_amdgcn_global_load_lds(
                (const __attribute__((address_space(1))) void*)gp,
                (__attribute__((address_space(3))) void*)lp, 16, 0, 0);
        }
    };

    float4 wr0, wr1;
    auto ldW = [&](int c) {
        const int kb = k0 + c * KC;
        wr0 = *(const float4*)(W + (size_t)we * DD + kb + wsg * 8);
        wr1 = *(const float4*)(W + (size_t)we * DD + kb + wsg * 8 + 4);
    };
    auto stW = [&](int p) {
        const float v[8] = {wr0.x, wr0.y, wr0.z, wr0.w,
                            wr1.x, wr1.y, wr1.z, wr1.w};
        short8 h, l;
#pragma unroll
        for (int i = 0; i < 8; i++) {
            unsigned short hh = f2bf(v[i]);
            h[i] = (short)hh;
            l[i] = (short)f2bf(v[i] - bf2f(hh));
        }
        *(short8*)&whs[p][we * WSTR + wsg * 8] = h;
        *(short8*)&wls[p][we * WSTR + wsg * 8] = l;
    };

    auto compute = [&](int p) {
        short8 ah[2], al[2], bh[4], bl[4];
#pragma unroll
        for (int mf = 0; mf < 2; mf++) {
            const int r = (wv * 2 + mf) * 16 + fr;
            const int q = 4 * (fr & 7);          // r&7 == fr&7
            const float4 a0 = *(const float4*)&xs[p][r * 32 + ((fg * 8) ^ q)];
            const float4 a1 = *(const float4*)&xs[p][r * 32 + ((fg * 8 + 4) ^ q)];
            const float v[8] = {a0.x, a0.y, a0.z, a0.w, a1.x, a1.y, a1.z, a1.w};
#pragma unroll
            for (int i = 0; i < 8; i++) {
                unsigned short hh = f2bf(v[i]);
                ah[mf][i] = (short)hh;
                al[mf][i] = (short)f2bf(v[i] - bf2f(hh));
            }
        }
#pragma unroll
        for (int nt = 0; nt < 4; nt++) {
            const int e = nt * 16 + fr;
            bh[nt] = *(const short8*)&whs[p][e * WSTR + fg * 8];
            bl[nt] = *(const short8*)&wls[p][e * WSTR + fg * 8];
        }
#pragma unroll
        for (int mf = 0; mf < 2; mf++)
#pragma unroll
            for (int nt = 0; nt < 4; nt++) {
                accH[mf][nt] = __builtin_amdgcn_mfma_f32_16x16x32_bf16(
                    ah[mf], bh[nt], accH[mf][nt], 0, 0, 0);
                accL[mf][nt] = __builtin_amdgcn_mfma_f32_16x16x32_bf16(
                    ah[mf], bl[nt], accL[mf][nt], 0, 0, 0);
                accL[mf][nt] = __builtin_amdgcn_mfma_f32_16x16x32_bf16(
                    al[mf], bh[nt], accL[mf][nt], 0, 0, 0);
            }
    };

    const int nch = (DD / KS) / KC;      // 16
    ldW(0);
    stage_x(0, 0);
    stW(0);
    __syncthreads();                     // buf 0 staged & visible

    for (int c = 0; c < nch; c++) {
        const int p = c & 1;
        if (c + 1 < nch) {
            stage_x(p ^ 1, c + 1);       // async DMA into other buffer
            ldW(c + 1);                  // W regs in flight under compute
        }
        compute(p);
        if (c + 1 < nch) stW(p ^ 1);     // vmcnt wait auto-inserted here
        __syncthreads();                 // drain + visibility, once per step
    }

    // C/D (verified m89/m91): col = lane&15 -> expert, row = fg*4+j -> token
#pragma unroll
    for (int mf = 0; mf < 2; mf++)
#pragma unroll
        for (int nt = 0; nt < 4; nt++)
#pragma unroll
            for (int j = 0; j < 4; j++) {
                const int token = m0 + (wv * 2 + mf) * 16 + fg * 4 + j;
                const float v = accH[mf][nt][j] + accL[mf][nt][j];
                part[((size_t)ks * NTOK + token) * EE + nt * 16 + fr] = v;
            }

    // ---- split-K semaphore: last block of this m-group reduces ----
    __threadfence();                     // release: partials visible
    if (t == 0) {
        unsigned int old = (unsigned int)atomicAdd(&ready[mblk], 1);
        is_last = ((old % (unsigned)KS) == (unsigned)(KS - 1)) ? 1 : 0;
    }
    __syncthreads();
    if (!is_last) return;
    __threadfence();                     // acquire: see all KS slices

    const float blv = bias[lane];
    for (int r = 0; r < 32; r++) {       // wave wv -> tokens wv*32+r
        const int tok = m0 + wv * 32 + r;
        float v = blv;
#pragma unroll
        for (int k2 = 0; k2 < KS; k2++)  // fixed order: deterministic
            v += part[((size_t)k2 * NTOK + tok) * EE + lane];

        float m1 = v;
#pragma unroll
        for (int off = 1; off < 64; off <<= 1) m1 = fmaxf(m1, __shfl_xor(m1, off));
        const unsigned long long b1 = __ballot(v == m1);
        const int i1 = (int)__ffsll(b1) - 1;          // lowest index (jax)

        const float vm2 = (lane == i1) ? -3.4e38f : v;
        float m2 = vm2;
#pragma unroll
        for (int off = 1; off < 64; off <<= 1) m2 = fmaxf(m2, __shfl_xor(m2, off));
        const unsigned long long b2 = __ballot(vm2 == m2 && lane != i1);
        const int i2 = (int)__ffsll(b2) - 1;

        const float vm3 = (lane == i1 || lane == i2) ? -3.4e38f : v;
        float m3 = vm3;
#pragma unroll
        for (int off = 1; off < 64; off <<= 1) m3 = fmaxf(m3, __shfl_xor(m3, off));

        if (lane == 0) {
            flag[tok] = ((m1 - m2 < TAU) || (m2 - m3 < TAU)) ? 1 : 0;
            double ex = exp((double)m2 - (double)m1);  // m1 >= m2 -> stable
            double s  = 1.0 + ex;
            out[tok * 2 + 0] = (float)(1.0 / s);
            out[tok * 2 + 1] = (float)(ex / s);
            out[NTOK * 2 + tok * 2 + 0] = (float)i1;
            out[NTOK * 2 + tok * 2 + 1] = (float)i2;
        }
    }
}

// ---------------------------------------------------------------------------
// fix: exact f64 recompute of flagged rows. Grid 256, block 1024; block b
// owns tokens b + i*256 (i=0..31); flags preloaded to LDS (block-uniform
// branch). x row staged in LDS; 16 lanes/expert -> coalesced 64B W reads;
// shfl-tree reduce -> wave 0 f64 top-2 (validated comparator).
// ---------------------------------------------------------------------------
__global__ __launch_bounds__(1024) void moirai_fix(
        const float* __restrict__ x, const float* __restrict__ W,
        const float* __restrict__ bias,
        const unsigned char* __restrict__ flag,
        float* __restrict__ out) {
    __shared__ float  xsr[DD];      // 16 KB
    __shared__ double red[EE];
    __shared__ unsigned char flg[32];

    const int t = threadIdx.x;
    const int e = t >> 4;           // expert 0..63
    const int j = t & 15;           // k-strip within expert

    if (t < 32) flg[t] = flag[blockIdx.x + t * 256];
    __syncthreads();

    for (int i = 0; i < 32; i++) {
        if (!flg[i]) continue;                 // block-uniform
        const int token = blockIdx.x + i * 256;

        *(float4*)&xsr[t * 4] = *(const float4*)(x + (size_t)token * DD + t * 4);
        __syncthreads();

        const float* wr = W + (size_t)e * DD;
        double a0 = 0.0, a1 = 0.0, a2 = 0.0, a3 = 0.0;
#pragma unroll 8
        for (int ii = 0; ii < DD / 64; ii++) {
            const int k = ii * 64 + j * 4;
            const float4 xv = *(const float4*)&xsr[k];
            const float4 wv = *(const float4*)(wr + k);
            a0 += (double)xv.x * (double)wv.x;
            a1 += (double)xv.y * (double)wv.y;
            a2 += (double)xv.z * (double)wv.z;
            a3 += (double)xv.w * (double)wv.w;
        }
        double s = (a0 + a1) + (a2 + a3);
#pragma unroll
        for (int off = 1; off < 16; off <<= 1)
            s += __shfl_xor(s, off);           // within 16-lane group
        if (j == 0) red[e] = s;
        __syncthreads();

        if (t < 64) {                          // wave 0: f64 top-2
            double vd = red[t] + (double)bias[t];
            double e1 = vd, e2 = -1.0e300;
            int    f1 = t,  f2 = 127;
#pragma unroll
            for (int off = 1; off < 64; off <<= 1) {
                double u1 = __shfl_xor(e1, off);
                double u2 = __shfl_xor(e2, off);
                int    j1 = __shfl_xor(f1, off);
                int    j2 = __shfl_xor(f2, off);
                bool u1_beats_e1 = (u1 > e1) || (u1 == e1 && j1 < f1);
                if (u1_beats_e1) {
                    bool e1_beats_u2 = (e1 > u2) || (e1 == u2 && f1 < j2);
                    if (e1_beats_u2) { e2 = e1; f2 = f1; }
                    else             { e2 = u2; f2 = j2; }
                    e1 = u1; f1 = j1;
                } else {
                    bool u1_beats_e2 = (u1 > e2) || (u1 == e2 && j1 < f2);
                    if (u1_beats_e2) { e2 = u1; f2 = j1; }
                }
            }
            if (t == 0) {
                double ex = exp(e2 - e1);
                double sm = 1.0 + ex;
                out[token * 2 + 0] = (float)(1.0 / sm);
                out[token * 2 + 1] = (float)(ex / sm);
                out[NTOK * 2 + token * 2 + 0] = (float)f1;
                out[NTOK * 2 + token * 2 + 1] = (float)f2;
            }
        }
        __syncthreads();   // LDS reuse guard
    }
}

// ---------------------------------------------------------------------------
extern "C" void kernel_launch(void* const* d_in, const int* in_sizes, int n_in,
                              void* d_out, int out_size, void* d_ws, size_t ws_size,
                              hipStream_t stream) {
    const float* x = (const float*)d_in[0];
    const float* W = (const float*)d_in[1];
    const float* b = (const float*)d_in[2];
    float* out = (float*)d_out;

    // ws layout: [ready: 64 int][flag: 8192 B] padded to 64 KB, then partials.
    // ready is never reset: trigger is UNSIGNED (old % KS == KS-1), correct
    // for any initial value (incl. 0xAA poison). flag fully overwritten/call.
    const size_t HDR = 65536;
    int*           ready = (int*)d_ws;
    unsigned char* flag  = (unsigned char*)d_ws + 256;
    float*         part  = (float*)((char*)d_ws + HDR);

    moirai_gemm<<<NMB * KS, 256, 0, stream>>>(x, W, b, part, ready, flag, out);
    moirai_fix<<<256, 1024, 0, stream>>>(x, W, b, flag, out);
}

// Round 19
// 82.553 us; speedup vs baseline: 5.2098x; 2.1825x over previous
//
#include <hip/hip_runtime.h>
#include <math.h>

#define DD 4096
#define EE 64
#define NTOK 8192
#define BM 128           // tokens per block
#define KC 32            // K-chunk per pipeline step
#define NMB (NTOK / BM)  // 64 m-blocks
#define KS 8             // K-split
#define WSTR 40          // W LDS row stride in bf16 (80 B, 16B-aligned)
#define TAU 4e-3f        // near-tie flag threshold (split err ~1e-5 RMS)

typedef __attribute__((ext_vector_type(8))) short short8;
typedef __attribute__((ext_vector_type(4))) float f32x4;

__device__ __forceinline__ unsigned short f2bf(float f) {   // RNE bf16
    unsigned int u = __float_as_uint(f);
    return (unsigned short)((u + 0x7FFFu + ((u >> 16) & 1u)) >> 16);
}
__device__ __forceinline__ float bf2f(unsigned short h) {
    return __uint_as_float((unsigned int)h << 16);
}

// ---------------------------------------------------------------------------
// gemm (r13 champion structure, no prep): 3-term split-bf16 MFMA, merged acc.
// Block = 256 thr (4 waves) = 128 tok x 64 exp x K-slice. Wave wv: m-frags
// {2wv,2wv+1}, n-frags 0..3 -> 24 MFMA per K=32 step.
// x: global_load_lds dwordx4 x16/step, src-swizzled k^4*(r&7) -> conflict-
//    free ds_read_b128 fragments; cvt f32->bf16 hi/lo at read.
// W: f32 global->reg->cvt hi/lo->ds_write per step (stride-40 rows).
// ONE __syncthreads per step. NO fences/atomics (r18 lesson: device-scope
// fences cost ~140us; the kernel boundary is the cheap device barrier).
// Partials -> part[ks][token][e].
// ---------------------------------------------------------------------------
__global__ __launch_bounds__(256, 2) void moirai_gemm(
        const float* __restrict__ x,
        const float* __restrict__ W,
        float* __restrict__ part) {
    __shared__ __align__(16) float          xs[2][BM * KC];     // 32 KB
    __shared__ __align__(16) unsigned short whs[2][EE * WSTR];  // 10 KB
    __shared__ __align__(16) unsigned short wls[2][EE * WSTR];  // 10 KB

    const int t    = threadIdx.x;
    const int lane = t & 63;
    const int wv   = t >> 6;             // wave 0..3
    const int mblk = blockIdx.x & (NMB - 1);
    const int ks   = blockIdx.x >> 6;    // grid = NMB * KS
    const int m0   = mblk * BM;
    const int k0   = ks * (DD / KS);

    const int fr = lane & 15;            // fragment row (token / expert)
    const int fg = lane >> 4;            // k-group (8 elems)

    const int we  = t >> 2;              // W staging: row 0..63
    const int wsg = t & 3;               // 8-elem segment 0..3

    f32x4 accH[2][4], accL[2][4];
#pragma unroll
    for (int mf = 0; mf < 2; mf++)
#pragma unroll
        for (int nt = 0; nt < 4; nt++) {
            accH[mf][nt] = f32x4{0.f, 0.f, 0.f, 0.f};
            accL[mf][nt] = f32x4{0.f, 0.f, 0.f, 0.f};
        }

    // x staging: wave wv issues 4 global_load_lds (1 KB each, LDS-linear).
    auto stage_x = [&](int p, int c) {
        const int kb = k0 + c * KC;
#pragma unroll
        for (int j = 0; j < 4; j++) {
            const int r = wv * 32 + j * 8 + (lane >> 3);
            const int k = ((lane & 7) * 4) ^ (4 * (r & 7));
            const float* gp = x + (size_t)(m0 + r) * DD + kb + k;
            float* lp = &xs[p][(wv * 4 + j) * 256];   // wave-uniform base
            __builtin_amdgcn_global_load_lds(
                (const __attribute__((address_space(1))) void*)gp,
                (__attribute__((address_space(3))) void*)lp, 16, 0, 0);
        }
    };

    float4 wr0, wr1;
    auto ldW = [&](int c) {
        const int kb = k0 + c * KC;
        wr0 = *(const float4*)(W + (size_t)we * DD + kb + wsg * 8);
        wr1 = *(const float4*)(W + (size_t)we * DD + kb + wsg * 8 + 4);
    };
    auto stW = [&](int p) {
        const float v[8] = {wr0.x, wr0.y, wr0.z, wr0.w,
                            wr1.x, wr1.y, wr1.z, wr1.w};
        short8 h, l;
#pragma unroll
        for (int i = 0; i < 8; i++) {
            unsigned short hh = f2bf(v[i]);
            h[i] = (short)hh;
            l[i] = (short)f2bf(v[i] - bf2f(hh));
        }
        *(short8*)&whs[p][we * WSTR + wsg * 8] = h;
        *(short8*)&wls[p][we * WSTR + wsg * 8] = l;
    };

    auto compute = [&](int p) {
        short8 ah[2], al[2], bh[4], bl[4];
#pragma unroll
        for (int mf = 0; mf < 2; mf++) {
            const int r = (wv * 2 + mf) * 16 + fr;
            const int q = 4 * (fr & 7);          // r&7 == fr&7
            const float4 a0 = *(const float4*)&xs[p][r * 32 + ((fg * 8) ^ q)];
            const float4 a1 = *(const float4*)&xs[p][r * 32 + ((fg * 8 + 4) ^ q)];
            const float v[8] = {a0.x, a0.y, a0.z, a0.w, a1.x, a1.y, a1.z, a1.w};
#pragma unroll
            for (int i = 0; i < 8; i++) {
                unsigned short hh = f2bf(v[i]);
                ah[mf][i] = (short)hh;
                al[mf][i] = (short)f2bf(v[i] - bf2f(hh));
            }
        }
#pragma unroll
        for (int nt = 0; nt < 4; nt++) {
            const int e = nt * 16 + fr;
            bh[nt] = *(const short8*)&whs[p][e * WSTR + fg * 8];
            bl[nt] = *(const short8*)&wls[p][e * WSTR + fg * 8];
        }
#pragma unroll
        for (int mf = 0; mf < 2; mf++)
#pragma unroll
            for (int nt = 0; nt < 4; nt++) {
                accH[mf][nt] = __builtin_amdgcn_mfma_f32_16x16x32_bf16(
                    ah[mf], bh[nt], accH[mf][nt], 0, 0, 0);
                accL[mf][nt] = __builtin_amdgcn_mfma_f32_16x16x32_bf16(
                    ah[mf], bl[nt], accL[mf][nt], 0, 0, 0);
                accL[mf][nt] = __builtin_amdgcn_mfma_f32_16x16x32_bf16(
                    al[mf], bh[nt], accL[mf][nt], 0, 0, 0);
            }
    };

    const int nch = (DD / KS) / KC;      // 16
    ldW(0);
    stage_x(0, 0);
    stW(0);
    __syncthreads();                     // buf 0 staged & visible

    for (int c = 0; c < nch; c++) {
        const int p = c & 1;
        if (c + 1 < nch) {
            stage_x(p ^ 1, c + 1);       // async DMA into other buffer
            ldW(c + 1);                  // W regs in flight under compute
        }
        compute(p);
        if (c + 1 < nch) stW(p ^ 1);     // vmcnt wait auto-inserted here
        __syncthreads();                 // drain + visibility, once per step
    }

    // C/D (verified m89/m91): col = lane&15 -> expert, row = fg*4+j -> token
#pragma unroll
    for (int mf = 0; mf < 2; mf++)
#pragma unroll
        for (int nt = 0; nt < 4; nt++)
#pragma unroll
            for (int j = 0; j < 4; j++) {
                const int token = m0 + (wv * 2 + mf) * 16 + fg * 4 + j;
                const float v = accH[mf][nt][j] + accL[mf][nt][j];
                part[((size_t)ks * NTOK + token) * EE + nt * 16 + fr] = v;
            }
}

// ---------------------------------------------------------------------------
// topk: wave per token, lane = expert. f32 sum of KS partials (fixed order,
// deterministic) + bias -> ballot top-3 (lowest-index tie-break = jax).
// flag[token] written unconditionally (0/1) -> no reset, poison-immune.
// Output: [gate_probs 16384 f32][indices-as-f32 16384].
// ---------------------------------------------------------------------------
__global__ void moirai_topk(const float* __restrict__ part,
                            const float* __restrict__ bias,
                            float* __restrict__ out,
                            unsigned char* __restrict__ flag) {
    const int lane  = threadIdx.x & 63;
    const int token = blockIdx.x * 4 + (threadIdx.x >> 6);

    float v = bias[lane];
#pragma unroll
    for (int ks = 0; ks < KS; ks++)
        v += part[((size_t)ks * NTOK + token) * EE + lane];

    float m1 = v;
#pragma unroll
    for (int off = 1; off < 64; off <<= 1) m1 = fmaxf(m1, __shfl_xor(m1, off));
    const unsigned long long b1 = __ballot(v == m1);
    const int i1 = (int)__ffsll(b1) - 1;              // lowest index (jax)

    const float vm2 = (lane == i1) ? -3.4e38f : v;
    float m2 = vm2;
#pragma unroll
    for (int off = 1; off < 64; off <<= 1) m2 = fmaxf(m2, __shfl_xor(m2, off));
    const unsigned long long b2 = __ballot(vm2 == m2 && lane != i1);
    const int i2 = (int)__ffsll(b2) - 1;

    const float vm3 = (lane == i1 || lane == i2) ? -3.4e38f : v;
    float m3 = vm3;
#pragma unroll
    for (int off = 1; off < 64; off <<= 1) m3 = fmaxf(m3, __shfl_xor(m3, off));

    if (lane == 0) {
        flag[token] = ((m1 - m2 < TAU) || (m2 - m3 < TAU)) ? 1 : 0;
        double ex = exp((double)m2 - (double)m1);     // m1 >= m2 -> stable
        double s  = 1.0 + ex;
        out[token * 2 + 0] = (float)(1.0 / s);
        out[token * 2 + 1] = (float)(ex / s);
        out[NTOK * 2 + token * 2 + 0] = (float)i1;
        out[NTOK * 2 + token * 2 + 1] = (float)i2;
    }
}

// ---------------------------------------------------------------------------
// fix: exact f64 recompute of flagged rows. Grid 256, block 1024; block b
// owns tokens b + i*256; flags preloaded to LDS (block-uniform branch).
// x row staged in LDS; 16 lanes/expert -> coalesced 64B W reads;
// shfl-tree reduce -> wave 0 f64 top-2 (validated comparator).
// ---------------------------------------------------------------------------
__global__ __launch_bounds__(1024) void moirai_fix(
        const float* __restrict__ x, const float* __restrict__ W,
        const float* __restrict__ bias,
        const unsigned char* __restrict__ flag,
        float* __restrict__ out) {
    __shared__ float  xsr[DD];      // 16 KB
    __shared__ double red[EE];
    __shared__ unsigned char flg[32];

    const int t = threadIdx.x;
    const int e = t >> 4;           // expert 0..63
    const int j = t & 15;           // k-strip within expert

    if (t < 32) flg[t] = flag[blockIdx.x + t * 256];
    __syncthreads();

    for (int i = 0; i < 32; i++) {
        if (!flg[i]) continue;                 // block-uniform
        const int token = blockIdx.x + i * 256;

        *(float4*)&xsr[t * 4] = *(const float4*)(x + (size_t)token * DD + t * 4);
        __syncthreads();

        const float* wr = W + (size_t)e * DD;
        double a0 = 0.0, a1 = 0.0, a2 = 0.0, a3 = 0.0;
#pragma unroll 8
        for (int ii = 0; ii < DD / 64; ii++) {
            const int k = ii * 64 + j * 4;
            const float4 xv = *(const float4*)&xsr[k];
            const float4 wv = *(const float4*)(wr + k);
            a0 += (double)xv.x * (double)wv.x;
            a1 += (double)xv.y * (double)wv.y;
            a2 += (double)xv.z * (double)wv.z;
            a3 += (double)xv.w * (double)wv.w;
        }
        double s = (a0 + a1) + (a2 + a3);
#pragma unroll
        for (int off = 1; off < 16; off <<= 1)
            s += __shfl_xor(s, off);           // within 16-lane group
        if (j == 0) red[e] = s;
        __syncthreads();

        if (t < 64) {                          // wave 0: f64 top-2
            double vd = red[t] + (double)bias[t];
            double e1 = vd, e2 = -1.0e300;
            int    f1 = t,  f2 = 127;
#pragma unroll
            for (int off = 1; off < 64; off <<= 1) {
                double u1 = __shfl_xor(e1, off);
                double u2 = __shfl_xor(e2, off);
                int    j1 = __shfl_xor(f1, off);
                int    j2 = __shfl_xor(f2, off);
                bool u1_beats_e1 = (u1 > e1) || (u1 == e1 && j1 < f1);
                if (u1_beats_e1) {
                    bool e1_beats_u2 = (e1 > u2) || (e1 == u2 && f1 < j2);
                    if (e1_beats_u2) { e2 = e1; f2 = f1; }
                    else             { e2 = u2; f2 = j2; }
                    e1 = u1; f1 = j1;
                } else {
                    bool u1_beats_e2 = (u1 > e2) || (u1 == e2 && j1 < f2);
                    if (u1_beats_e2) { e2 = u1; f2 = j1; }
                }
            }
            if (t == 0) {
                double ex = exp(e2 - e1);
                double sm = 1.0 + ex;
                out[token * 2 + 0] = (float)(1.0 / sm);
                out[token * 2 + 1] = (float)(ex / sm);
                out[NTOK * 2 + token * 2 + 0] = (float)f1;
                out[NTOK * 2 + token * 2 + 1] = (float)f2;
            }
        }
        __syncthreads();   // LDS reuse guard
    }
}

// ---------------------------------------------------------------------------
extern "C" void kernel_launch(void* const* d_in, const int* in_sizes, int n_in,
                              void* d_out, int out_size, void* d_ws, size_t ws_size,
                              hipStream_t stream) {
    const float* x = (const float*)d_in[0];
    const float* W = (const float*)d_in[1];
    const float* b = (const float*)d_in[2];
    float* out = (float*)d_out;

    // ws layout: [flag: 8192 B, padded to 64 KB][partials].
    // flag fully overwritten by topk each call -> no reset, poison-immune.
    const size_t HDR = 65536;
    unsigned char* flag = (unsigned char*)d_ws;
    float*         part = (float*)((char*)d_ws + HDR);

    moirai_gemm<<<NMB * KS, 256, 0, stream>>>(x, W, part);
    moirai_topk<<<NTOK / 4, 256, 0, stream>>>(part, b, out, flag);
    moirai_fix<<<256, 1024, 0, stream>>>(x, W, b, flag, out);
}